// Round 1
// baseline (864.033 us; speedup 1.0000x reference)
//
#include <hip/hip_runtime.h>

// Problem constants (match reference)
constexpr int N_ = 512, D_ = 64, C_ = 32, HID_ = 128, HEADS_ = 8, HD_ = 16;
constexpr int DP_ = D_ + 4;          // padded weight row (bank-conflict-free, keeps 16B align)
constexpr float SCALE_ = 0.25f;      // HEAD_DIM^-0.5

// One block per (b,t,h). 256 threads = 4 waves.
// LDS: k[512][16] + v[512][16] + 3 * w[16][68]  = 19648 floats = 76.75 KB -> 2 blocks/CU.
__global__ __launch_bounds__(256, 2)
void spatial_attn_kernel(const float* __restrict__ x,
                         const float* __restrict__ cls_map,
                         const float* __restrict__ Wq,
                         const float* __restrict__ Wk,
                         const float* __restrict__ Wv,
                         float* __restrict__ out) {
    __shared__ float kk[N_ * HD_];     // K tile; reused as sx after attention
    __shared__ float vv[N_ * HD_];     // V tile
    __shared__ float wq_s[HD_ * DP_];
    __shared__ float wk_s[HD_ * DP_];
    __shared__ float wv_s[HD_ * DP_];

    const int tid = threadIdx.x;
    const int blk = blockIdx.x;
    const int h  = blk & (HEADS_ - 1);
    const int bt = blk >> 3;           // 0..95

    const float* __restrict__ xbt = x + (size_t)bt * N_ * D_;
    const float* __restrict__ cls = cls_map + (size_t)bt * C_ * N_;
    float* __restrict__ obt       = out + (size_t)bt * C_ * HID_;

    // ---- stage head weight slices into LDS (rows padded to DP_) ----
    {
        const float* gq = Wq + h * HD_ * D_;
        const float* gk = Wk + h * HD_ * D_;
        const float* gv = Wv + h * HD_ * D_;
        for (int idx = tid; idx < HD_ * D_; idx += 256) {
            const int r = idx >> 6, c2 = idx & 63;
            wq_s[r * DP_ + c2] = gq[idx];
            wk_s[r * DP_ + c2] = gk[idx];
            wv_s[r * DP_ + c2] = gv[idx];
        }
    }
    __syncthreads();

    // ---- K/V projection into LDS ----
    // thread -> (row-offset rr 0..15, col j 0..15); 32 row-groups of 16
    {
        const int j  = tid & 15;
        const int rr = tid >> 4;
        const float4* wkr = (const float4*)(wk_s + j * DP_);
        const float4* wvr = (const float4*)(wv_s + j * DP_);
        for (int nn = 0; nn < N_; nn += 16) {
            const int n = nn + rr;
            const float4* xr = (const float4*)(xbt + n * D_);
            float4 pk = {0.f,0.f,0.f,0.f}, pv = {0.f,0.f,0.f,0.f};
#pragma unroll
            for (int d4 = 0; d4 < 16; ++d4) {
                const float4 xv = xr[d4];
                const float4 a  = wkr[d4];
                const float4 b  = wvr[d4];
                pk.x += xv.x*a.x; pk.y += xv.y*a.y; pk.z += xv.z*a.z; pk.w += xv.w*a.w;
                pv.x += xv.x*b.x; pv.y += xv.y*b.y; pv.z += xv.z*b.z; pv.w += xv.w*b.w;
            }
            kk[n * HD_ + j] = (pk.x + pk.y) + (pk.z + pk.w);
            vv[n * HD_ + j] = (pv.x + pv.y) + (pv.z + pv.w);
        }
    }

    // ---- Q rows for this thread: n0 = tid, n1 = tid + 256 (SCALE folded in) ----
    float q0a[16], q1a[16];
    {
        // row n0
        {
            const float4* xr = (const float4*)(xbt + tid * D_);
            float4 xa[16];
#pragma unroll
            for (int d4 = 0; d4 < 16; ++d4) xa[d4] = xr[d4];
#pragma unroll
            for (int jj = 0; jj < HD_; ++jj) {
                const float4* wr = (const float4*)(wq_s + jj * DP_);
                float4 p = {0.f,0.f,0.f,0.f};
#pragma unroll
                for (int d4 = 0; d4 < 16; ++d4) {
                    const float4 w4 = wr[d4];
                    p.x += xa[d4].x*w4.x; p.y += xa[d4].y*w4.y;
                    p.z += xa[d4].z*w4.z; p.w += xa[d4].w*w4.w;
                }
                q0a[jj] = ((p.x + p.y) + (p.z + p.w)) * SCALE_;
            }
        }
        // row n1
        {
            const float4* xr = (const float4*)(xbt + (tid + 256) * D_);
            float4 xa[16];
#pragma unroll
            for (int d4 = 0; d4 < 16; ++d4) xa[d4] = xr[d4];
#pragma unroll
            for (int jj = 0; jj < HD_; ++jj) {
                const float4* wr = (const float4*)(wq_s + jj * DP_);
                float4 p = {0.f,0.f,0.f,0.f};
#pragma unroll
                for (int d4 = 0; d4 < 16; ++d4) {
                    const float4 w4 = wr[d4];
                    p.x += xa[d4].x*w4.x; p.y += xa[d4].y*w4.y;
                    p.z += xa[d4].z*w4.z; p.w += xa[d4].w*w4.w;
                }
                q1a[jj] = ((p.x + p.y) + (p.z + p.w)) * SCALE_;
            }
        }
    }

    // ---- attention: online accumulate exp(s)*v, denom; no max-shift needed (|s| small) ----
    float acc0[16], acc1[16];
#pragma unroll
    for (int i = 0; i < 16; ++i) { acc0[i] = 0.f; acc1[i] = 0.f; }
    float den0 = 0.f, den1 = 0.f;

    __syncthreads();   // kk/vv fully written

    for (int m = 0; m < N_; ++m) {
        const float4* kf = (const float4*)(kk + m * HD_);  // broadcast reads
        const float4* vf = (const float4*)(vv + m * HD_);
        float4 pk0 = {0.f,0.f,0.f,0.f}, pk1 = {0.f,0.f,0.f,0.f};
#pragma unroll
        for (int i = 0; i < 4; ++i) {
            const float4 k4 = kf[i];
            pk0.x += q0a[4*i+0]*k4.x; pk0.y += q0a[4*i+1]*k4.y;
            pk0.z += q0a[4*i+2]*k4.z; pk0.w += q0a[4*i+3]*k4.w;
            pk1.x += q1a[4*i+0]*k4.x; pk1.y += q1a[4*i+1]*k4.y;
            pk1.z += q1a[4*i+2]*k4.z; pk1.w += q1a[4*i+3]*k4.w;
        }
        const float s0 = (pk0.x + pk0.y) + (pk0.z + pk0.w);
        const float s1 = (pk1.x + pk1.y) + (pk1.z + pk1.w);
        const float e0 = __expf(s0);
        const float e1 = __expf(s1);
        den0 += e0; den1 += e1;
#pragma unroll
        for (int i = 0; i < 4; ++i) {
            const float4 v4 = vf[i];
            acc0[4*i+0] += e0*v4.x; acc0[4*i+1] += e0*v4.y;
            acc0[4*i+2] += e0*v4.z; acc0[4*i+3] += e0*v4.w;
            acc1[4*i+0] += e1*v4.x; acc1[4*i+1] += e1*v4.y;
            acc1[4*i+2] += e1*v4.z; acc1[4*i+3] += e1*v4.w;
        }
    }

    __syncthreads();   // everyone done reading kk/vv

    // ---- normalize, write sx into kk's LDS region ----
    float* sx = kk;
    {
        const float r0 = 1.0f / den0, r1 = 1.0f / den1;
        float4* s0p = (float4*)(sx + (size_t)tid * HD_);
        float4* s1p = (float4*)(sx + (size_t)(tid + 256) * HD_);
#pragma unroll
        for (int i = 0; i < 4; ++i) {
            float4 a, b;
            a.x = acc0[4*i+0]*r0; a.y = acc0[4*i+1]*r0; a.z = acc0[4*i+2]*r0; a.w = acc0[4*i+3]*r0;
            b.x = acc1[4*i+0]*r1; b.y = acc1[4*i+1]*r1; b.z = acc1[4*i+2]*r1; b.w = acc1[4*i+3]*r1;
            s0p[i] = a;
            s1p[i] = b;
        }
    }
    __syncthreads();

    // ---- cls pooling: thread -> (c = tid>>3, d0 = tid&7) computes (c,d0) and (c,d0+8) ----
    {
        const int c  = tid >> 3;
        const int d0 = tid & 7;
        const float4* cr4 = (const float4*)(cls + c * N_);
        float p0a = 0.f, p0b = 0.f, p1a = 0.f, p1b = 0.f;
        for (int n4 = 0; n4 < N_ / 4; ++n4) {
            const float4 cm = cr4[n4];
            const int n = n4 * 4;
            p0a += cm.x * sx[(n+0)*HD_ + d0];
            p1a += cm.x * sx[(n+0)*HD_ + d0 + 8];
            p0b += cm.y * sx[(n+1)*HD_ + d0];
            p1b += cm.y * sx[(n+1)*HD_ + d0 + 8];
            p0a += cm.z * sx[(n+2)*HD_ + d0];
            p1a += cm.z * sx[(n+2)*HD_ + d0 + 8];
            p0b += cm.w * sx[(n+3)*HD_ + d0];
            p1b += cm.w * sx[(n+3)*HD_ + d0 + 8];
        }
        obt[c * HID_ + h * HD_ + d0]     = p0a + p0b;
        obt[c * HID_ + h * HD_ + d0 + 8] = p1a + p1b;
    }
}

extern "C" void kernel_launch(void* const* d_in, const int* in_sizes, int n_in,
                              void* d_out, int out_size, void* d_ws, size_t ws_size,
                              hipStream_t stream) {
    const float* x       = (const float*)d_in[0];
    const float* cls_map = (const float*)d_in[1];
    const float* Wq      = (const float*)d_in[2];
    const float* Wk      = (const float*)d_in[3];
    const float* Wv      = (const float*)d_in[4];
    float* out           = (float*)d_out;

    const int blocks = 96 * HEADS_;   // B*T*HEADS = 768
    spatial_attn_kernel<<<blocks, 256, 0, stream>>>(x, cls_map, Wq, Wk, Wv, out);
}

// Round 2
// 671.644 us; speedup vs baseline: 1.2864x; 1.2864x over previous
//
#include <hip/hip_runtime.h>

// Problem constants (match reference)
constexpr int N_ = 512, D_ = 64, C_ = 32, HID_ = 128, HEADS_ = 8, HD_ = 16;
constexpr int DP_ = D_ + 4;          // padded weight row (16B-aligned, conflict-free)
constexpr float SCALE_ = 0.25f;      // HEAD_DIM^-0.5  (folded into staged Wq)

// One block per (b,t,h). 256 threads = 4 waves.
// LDS: bufA[512*16] + bufB[512*16] + 3 * w[16][68] = 76.75 KB -> 2 blocks/CU.
// Register discipline: no thread ever holds a float4[16] array; all projections
// use the cooperative 8-reg accumulator pattern. Attention-loop live set ~90 VGPR.
__global__ __launch_bounds__(256, 2)
void spatial_attn_kernel(const float* __restrict__ x,
                         const float* __restrict__ cls_map,
                         const float* __restrict__ Wq,
                         const float* __restrict__ Wk,
                         const float* __restrict__ Wv,
                         float* __restrict__ out) {
    __shared__ float bufA[N_ * HD_];   // Q -> K -> sx (reused)
    __shared__ float bufB[N_ * HD_];   // V
    __shared__ float wq_s[HD_ * DP_];  // pre-scaled by SCALE_
    __shared__ float wk_s[HD_ * DP_];
    __shared__ float wv_s[HD_ * DP_];

    const int tid = threadIdx.x;
    const int h  = blockIdx.x & (HEADS_ - 1);
    const int bt = blockIdx.x >> 3;    // 0..95

    const float* __restrict__ xbt = x + (size_t)bt * N_ * D_;
    const float* __restrict__ cls = cls_map + (size_t)bt * C_ * N_;
    float* __restrict__ obt       = out + (size_t)bt * C_ * HID_;

    // ---- stage head weight slices into LDS (rows padded to DP_) ----
    {
        const float* gq = Wq + h * HD_ * D_;
        const float* gk = Wk + h * HD_ * D_;
        const float* gv = Wv + h * HD_ * D_;
        for (int idx = tid; idx < HD_ * D_; idx += 256) {
            const int r = idx >> 6, c2 = idx & 63;
            wq_s[r * DP_ + c2] = gq[idx] * SCALE_;   // fold attention scale into Wq
            wk_s[r * DP_ + c2] = gk[idx];
            wv_s[r * DP_ + c2] = gv[idx];
        }
    }
    __syncthreads();

    // thread -> (output channel j 0..15, row-offset rr 0..15)
    const int j  = tid & 15;
    const int rr = tid >> 4;

    // ---- pass 1: Q projection into bufA (cooperative, 8-reg accumulators) ----
    {
        const float4* wr = (const float4*)(wq_s + j * DP_);
        for (int nn = 0; nn < N_; nn += 16) {
            const int n = nn + rr;
            const float4* xr = (const float4*)(xbt + n * D_);
            float4 p = {0.f, 0.f, 0.f, 0.f};
#pragma unroll
            for (int d4 = 0; d4 < 16; ++d4) {
                const float4 xv = xr[d4];
                const float4 w4 = wr[d4];
                p.x += xv.x * w4.x; p.y += xv.y * w4.y;
                p.z += xv.z * w4.z; p.w += xv.w * w4.w;
            }
            bufA[n * HD_ + j] = (p.x + p.y) + (p.z + p.w);
        }
    }
    __syncthreads();

    // ---- pull this thread's two q rows (tid, tid+256) into registers ----
    float q0a[16], q1a[16];
    {
        const float4* a0 = (const float4*)(bufA + (size_t)tid * HD_);
        const float4* a1 = (const float4*)(bufA + (size_t)(tid + 256) * HD_);
#pragma unroll
        for (int i = 0; i < 4; ++i) {
            const float4 u = a0[i], w = a1[i];
            q0a[4*i+0] = u.x; q0a[4*i+1] = u.y; q0a[4*i+2] = u.z; q0a[4*i+3] = u.w;
            q1a[4*i+0] = w.x; q1a[4*i+1] = w.y; q1a[4*i+2] = w.z; q1a[4*i+3] = w.w;
        }
    }
    __syncthreads();   // everyone has q; safe to overwrite bufA with K

    // ---- pass 2: K and V projections (fused single sweep of x) ----
    {
        const float4* wkr = (const float4*)(wk_s + j * DP_);
        const float4* wvr = (const float4*)(wv_s + j * DP_);
        for (int nn = 0; nn < N_; nn += 16) {
            const int n = nn + rr;
            const float4* xr = (const float4*)(xbt + n * D_);
            float4 pk = {0.f,0.f,0.f,0.f}, pv = {0.f,0.f,0.f,0.f};
#pragma unroll
            for (int d4 = 0; d4 < 16; ++d4) {
                const float4 xv = xr[d4];
                const float4 a  = wkr[d4];
                const float4 b  = wvr[d4];
                pk.x += xv.x*a.x; pk.y += xv.y*a.y; pk.z += xv.z*a.z; pk.w += xv.w*a.w;
                pv.x += xv.x*b.x; pv.y += xv.y*b.y; pv.z += xv.z*b.z; pv.w += xv.w*b.w;
            }
            bufA[n * HD_ + j] = (pk.x + pk.y) + (pk.z + pk.w);
            bufB[n * HD_ + j] = (pv.x + pv.y) + (pv.z + pv.w);
        }
    }

    // ---- attention: online accumulate exp(s)*v and denom (|s| small, no max-shift) ----
    float acc0[16], acc1[16];
#pragma unroll
    for (int i = 0; i < 16; ++i) { acc0[i] = 0.f; acc1[i] = 0.f; }
    float den0 = 0.f, den1 = 0.f;

    __syncthreads();   // K/V fully written

    for (int m = 0; m < N_; ++m) {
        const float4* kf = (const float4*)(bufA + m * HD_);  // broadcast reads
        const float4* vf = (const float4*)(bufB + m * HD_);
        float4 pk0 = {0.f,0.f,0.f,0.f}, pk1 = {0.f,0.f,0.f,0.f};
#pragma unroll
        for (int i = 0; i < 4; ++i) {
            const float4 k4 = kf[i];
            pk0.x += q0a[4*i+0]*k4.x; pk0.y += q0a[4*i+1]*k4.y;
            pk0.z += q0a[4*i+2]*k4.z; pk0.w += q0a[4*i+3]*k4.w;
            pk1.x += q1a[4*i+0]*k4.x; pk1.y += q1a[4*i+1]*k4.y;
            pk1.z += q1a[4*i+2]*k4.z; pk1.w += q1a[4*i+3]*k4.w;
        }
        const float s0 = (pk0.x + pk0.y) + (pk0.z + pk0.w);
        const float s1 = (pk1.x + pk1.y) + (pk1.z + pk1.w);
        const float e0 = __expf(s0);
        const float e1 = __expf(s1);
        den0 += e0; den1 += e1;
#pragma unroll
        for (int i = 0; i < 4; ++i) {
            const float4 v4 = vf[i];
            acc0[4*i+0] += e0*v4.x; acc0[4*i+1] += e0*v4.y;
            acc0[4*i+2] += e0*v4.z; acc0[4*i+3] += e0*v4.w;
            acc1[4*i+0] += e1*v4.x; acc1[4*i+1] += e1*v4.y;
            acc1[4*i+2] += e1*v4.z; acc1[4*i+3] += e1*v4.w;
        }
    }

    __syncthreads();   // everyone done reading K/V

    // ---- normalize, write sx into bufA ----
    float* sx = bufA;
    {
        const float r0 = 1.0f / den0, r1 = 1.0f / den1;
        float4* s0p = (float4*)(sx + (size_t)tid * HD_);
        float4* s1p = (float4*)(sx + (size_t)(tid + 256) * HD_);
#pragma unroll
        for (int i = 0; i < 4; ++i) {
            float4 a, b;
            a.x = acc0[4*i+0]*r0; a.y = acc0[4*i+1]*r0; a.z = acc0[4*i+2]*r0; a.w = acc0[4*i+3]*r0;
            b.x = acc1[4*i+0]*r1; b.y = acc1[4*i+1]*r1; b.z = acc1[4*i+2]*r1; b.w = acc1[4*i+3]*r1;
            s0p[i] = a;
            s1p[i] = b;
        }
    }
    __syncthreads();

    // ---- cls pooling: thread -> (c = tid>>3, d0 = tid&7) owns d = {2*d0, 2*d0+1} ----
    {
        const int c  = tid >> 3;
        const int d0 = tid & 7;
        const float4* cr4 = (const float4*)(cls + c * N_);
        float px = 0.f, py = 0.f;
        for (int n4 = 0; n4 < N_ / 4; ++n4) {
            const float4 cm = cr4[n4];
            const int n = n4 * 4;
            const float2 s0 = *(const float2*)(sx + (n+0)*HD_ + 2*d0);
            const float2 s1 = *(const float2*)(sx + (n+1)*HD_ + 2*d0);
            const float2 s2 = *(const float2*)(sx + (n+2)*HD_ + 2*d0);
            const float2 s3 = *(const float2*)(sx + (n+3)*HD_ + 2*d0);
            px += cm.x * s0.x; py += cm.x * s0.y;
            px += cm.y * s1.x; py += cm.y * s1.y;
            px += cm.z * s2.x; py += cm.z * s2.y;
            px += cm.w * s3.x; py += cm.w * s3.y;
        }
        float2 o; o.x = px; o.y = py;
        *(float2*)(obt + c * HID_ + h * HD_ + 2 * d0) = o;
    }
}

extern "C" void kernel_launch(void* const* d_in, const int* in_sizes, int n_in,
                              void* d_out, int out_size, void* d_ws, size_t ws_size,
                              hipStream_t stream) {
    const float* x       = (const float*)d_in[0];
    const float* cls_map = (const float*)d_in[1];
    const float* Wq      = (const float*)d_in[2];
    const float* Wk      = (const float*)d_in[3];
    const float* Wv      = (const float*)d_in[4];
    float* out           = (float*)d_out;

    const int blocks = 96 * HEADS_;   // B*T*HEADS = 768
    spatial_attn_kernel<<<blocks, 256, 0, stream>>>(x, cls_map, Wq, Wk, Wv, out);
}

// Round 4
// 137.648 us; speedup vs baseline: 6.2771x; 4.8794x over previous
//
#include <hip/hip_runtime.h>

// Problem constants
constexpr int N_ = 512, D_ = 64, C_ = 32, HID_ = 128, HEADS_ = 8, HD_ = 16;
constexpr int BT_ = 96;
constexpr float LSCALE_ = 0.25f * 1.4426950408889634f;  // SCALE * log2(e), folded into Wq

typedef __attribute__((ext_vector_type(8))) short short8;
typedef __attribute__((ext_vector_type(4))) float f32x4;

union U8 { short8 s8; unsigned u[4]; };

static __device__ __forceinline__ unsigned short f2bf(float f) {
    unsigned u = __builtin_bit_cast(unsigned, f);
    unsigned r = (u + 0x7FFFu + ((u >> 16) & 1u)) >> 16;   // RNE
    return (unsigned short)r;
}

static __device__ __forceinline__ float fexp2(float x) {
#if __has_builtin(__builtin_amdgcn_exp2f)
    return __builtin_amdgcn_exp2f(x);
#else
    return exp2f(x);
#endif
}

// V key-permutation within each 32-block: storage pos p holds key kappa(p):
//   p = g*8+i, i<4 -> key g*4+i ; i>=4 -> key 16 + g*4 + (i-4)
static __device__ __forceinline__ int vperm(int b) {   // b = key % 32 -> storage pos
    return (b < 16) ? ((b >> 2) * 8 + (b & 3))
                    : (((b - 16) >> 2) * 8 + 4 + ((b - 16) & 3));
}

// ================= Kernel A: QKV projection (bf16 MFMA) =================
// grid 384 = bt(96) x rowblock(4 of 128 rows). 256 thr = 4 waves.
// out[m=channel][n=row] = sum_d W[ch][d] * x[row][d]
// Q/K stored row-major [bt][h][n][16] bf16; V stored [bt][h][d][n'] (transposed+permuted).
__global__ __launch_bounds__(256, 2)
void qkv_proj(const float* __restrict__ x,
              const float* __restrict__ Wq, const float* __restrict__ Wk,
              const float* __restrict__ Wv,
              unsigned short* __restrict__ qg, unsigned short* __restrict__ kg,
              unsigned short* __restrict__ vg) {
    __shared__ unsigned short xs[128 * 72];   // x tile bf16, row stride 72
    __shared__ unsigned short ws[384 * 72];   // W bf16 (Q:0-127, K:128-255, V:256-383)

    const int tid = threadIdx.x;
    const int bt = blockIdx.x >> 2, rb = blockIdx.x & 3;

    // stage W (fold LSCALE into Wq)
    for (int k = 0; k < 24; ++k) {
        const int f = tid + k * 256;              // float4 idx, 6144 total
        const int m = f >> 4, c4 = f & 15;
        const float* src = (m < 128) ? Wq : (m < 256 ? Wk : Wv);
        const float4 w4 = *(const float4*)(src + (m & 127) * 64 + c4 * 4);
        const float sc = (m < 128) ? LSCALE_ : 1.0f;
        uint2 t;
        t.x = f2bf(w4.x * sc) | ((unsigned)f2bf(w4.y * sc) << 16);
        t.y = f2bf(w4.z * sc) | ((unsigned)f2bf(w4.w * sc) << 16);
        *(uint2*)(ws + m * 72 + c4 * 4) = t;
    }
    // stage x tile
    const float* xb = x + ((size_t)bt * N_ + rb * 128) * D_;
    for (int k = 0; k < 8; ++k) {
        const int f = tid + k * 256;              // 2048 float4
        const int r = f >> 4, c4 = f & 15;
        const float4 v4 = *(const float4*)(xb + r * 64 + c4 * 4);
        uint2 t;
        t.x = f2bf(v4.x) | ((unsigned)f2bf(v4.y) << 16);
        t.y = f2bf(v4.z) | ((unsigned)f2bf(v4.w) << 16);
        *(uint2*)(xs + r * 72 + c4 * 4) = t;
    }
    __syncthreads();

    const int lane = tid & 63, w = tid >> 6;
    const int g = lane >> 4, l15 = lane & 15;

    for (int nt = 0; nt < 8; ++nt) {
        // B-frag: x^T  (B[k=dim][n=row], n = l15, k = g*8+i)
        const short8 b0 = *(const short8*)(xs + (nt * 16 + l15) * 72 + g * 8);
        const short8 b1 = *(const short8*)(xs + (nt * 16 + l15) * 72 + 32 + g * 8);
        for (int i = 0; i < 6; ++i) {
            const int mt = w * 6 + i;             // 0..23
            const unsigned short* wrow = ws + (mt * 16 + l15) * 72;
            const short8 a0 = *(const short8*)(wrow + g * 8);
            const short8 a1 = *(const short8*)(wrow + 32 + g * 8);
            f32x4 acc = {0.f, 0.f, 0.f, 0.f};
            acc = __builtin_amdgcn_mfma_f32_16x16x32_bf16(a0, b0, acc, 0, 0, 0);
            acc = __builtin_amdgcn_mfma_f32_16x16x32_bf16(a1, b1, acc, 0, 0, 0);
            // C layout: row(m)=channel = g*4+r, col(n)=x-row = l15
            const int mi = mt >> 3, h = mt & 7;
            const int nr = rb * 128 + nt * 16 + l15;          // row within bt
            const size_t hb = (size_t)bt * 8 + h;
            if (mi < 2) {
                unsigned short* dst = (mi == 0 ? qg : kg) + (hb * N_ + nr) * HD_ + g * 4;
                uint2 t;
                t.x = f2bf(acc[0]) | ((unsigned)f2bf(acc[1]) << 16);
                t.y = f2bf(acc[2]) | ((unsigned)f2bf(acc[3]) << 16);
                *(uint2*)dst = t;
            } else {
                unsigned short* dst = vg + hb * (N_ * HD_);   // [16][512] per head
                const int nn = (nr & ~31) + vperm(nr & 31);
#pragma unroll
                for (int r = 0; r < 4; ++r)
                    dst[(g * 4 + r) * N_ + nn] = f2bf(acc[r]);
            }
        }
    }
}

// ================= Kernel B: fused attention + cls pooling =================
// grid 768, XCD-swizzled: all 8 heads of a bt on one XCD.
__global__ __launch_bounds__(256)
void attn_pool(const unsigned short* __restrict__ qg,
               const unsigned short* __restrict__ kg,
               const unsigned short* __restrict__ vg,
               const float* __restrict__ cls_map,
               float* __restrict__ out) {
    __shared__ unsigned short k_lds[512 * 20];  // K rows, stride 20 bf16 (conflict-free)
    __shared__ unsigned short vt[16 * 520];     // V^T permuted, stride 520
    __shared__ float den[512];                  // 1/denominator per query row

    const int tid = threadIdx.x;
    const int xcd = blockIdx.x & 7, slot = blockIdx.x >> 3;
    const int bt = xcd * 12 + (slot % 12), h = slot / 12;
    const size_t hb = (size_t)bt * 8 + h;
    const unsigned short* Kg = kg + hb * (N_ * HD_);
    const unsigned short* Vg = vg + hb * (N_ * HD_);
    const unsigned short* Qg = qg + hb * (N_ * HD_);

    // stage K: 2048 8B-chunks covering all 512 rows x 16 dims  (BUGFIX vs r3:
    // previous loop staged only dims {0-3,8-11}, leaving half of k_lds
    // uninitialized -> NaN)
    for (int k = 0; k < 8; ++k) {
        const int c = tid + k * 256;            // 0..2047
        const int row = c >> 2, q = c & 3;
        const uint2 d = *(const uint2*)(Kg + row * 16 + q * 4);
        *(uint2*)(k_lds + row * 20 + q * 4) = d;
    }
    // stage Vt: 1024 16B-chunks, restripe 512 -> 520
    for (int k = 0; k < 4; ++k) {
        const int c = tid + k * 256;
        const int d_ = c >> 6, col = (c & 63) * 8;
        const uint4 v4 = *(const uint4*)(Vg + d_ * 512 + col);
        *(uint4*)(vt + d_ * 520 + col) = v4;
    }

    const int lane = tid & 63, w = tid >> 6;
    const int g = lane >> 4, l15 = lane & 15;
    const int qbase = w * 128;

    // Q-frags direct from global (B[k=dim][n=q]; dims 16..31 are zero-pad)
    short8 qf[8];
#pragma unroll
    for (int mb = 0; mb < 8; ++mb) {
        U8 f; f.u[0] = f.u[1] = f.u[2] = f.u[3] = 0u;
        if (g < 2) {
            const uint4 q4 = *(const uint4*)(Qg + (qbase + mb * 16 + l15) * 16 + g * 8);
            f.u[0] = q4.x; f.u[1] = q4.y; f.u[2] = q4.z; f.u[3] = q4.w;
        }
        qf[mb] = f.s8;
    }
    __syncthreads();

    f32x4 oacc[8];
    float dd[8];
#pragma unroll
    for (int mb = 0; mb < 8; ++mb) {
        oacc[mb] = (f32x4){0.f, 0.f, 0.f, 0.f};
        dd[mb] = 0.f;
    }
    const f32x4 zf = {0.f, 0.f, 0.f, 0.f};

    for (int j = 0; j < 16; ++j) {               // 32 keys per iter
        U8 ka, kb;
        ka.u[0] = ka.u[1] = ka.u[2] = ka.u[3] = 0u;
        kb.u[0] = kb.u[1] = kb.u[2] = kb.u[3] = 0u;
        if (g < 2) {                             // A[m=key][k=dim], dims 16..31 zero
            const unsigned short* r0 = k_lds + (j * 32 + l15) * 20 + g * 8;
            const unsigned short* r1 = k_lds + (j * 32 + 16 + l15) * 20 + g * 8;
            uint2 lo = *(const uint2*)r0, hi = *(const uint2*)(r0 + 4);
            ka.u[0] = lo.x; ka.u[1] = lo.y; ka.u[2] = hi.x; ka.u[3] = hi.y;
            lo = *(const uint2*)r1; hi = *(const uint2*)(r1 + 4);
            kb.u[0] = lo.x; kb.u[1] = lo.y; kb.u[2] = hi.x; kb.u[3] = hi.y;
        }
        // B-frag for PV: V[key-slot][d] from permuted Vt
        const short8 vf = *(const short8*)(vt + l15 * 520 + j * 32 + g * 8);

#pragma unroll
        for (int mb = 0; mb < 8; ++mb) {
            f32x4 s0 = __builtin_amdgcn_mfma_f32_16x16x32_bf16(ka.s8, qf[mb], zf, 0, 0, 0);
            f32x4 s1 = __builtin_amdgcn_mfma_f32_16x16x32_bf16(kb.s8, qf[mb], zf, 0, 0, 0);
            // lane holds S^T: keys j*32 + {g*4+r} (s0) and j*32+16+{g*4+r} (s1), q = l15
            float e0 = fexp2(s0[0]), e1 = fexp2(s0[1]), e2 = fexp2(s0[2]), e3 = fexp2(s0[3]);
            float e4 = fexp2(s1[0]), e5 = fexp2(s1[1]), e6 = fexp2(s1[2]), e7 = fexp2(s1[3]);
            dd[mb] += ((e0 + e1) + (e2 + e3)) + ((e4 + e5) + (e6 + e7));
            U8 p;
            p.u[0] = f2bf(e0) | ((unsigned)f2bf(e1) << 16);
            p.u[1] = f2bf(e2) | ((unsigned)f2bf(e3) << 16);
            p.u[2] = f2bf(e4) | ((unsigned)f2bf(e5) << 16);
            p.u[3] = f2bf(e6) | ((unsigned)f2bf(e7) << 16);
            oacc[mb] = __builtin_amdgcn_mfma_f32_16x16x32_bf16(p.s8, vf, oacc[mb], 0, 0, 0);
        }
    }

    // denominator: reduce across the 4 lane-groups, write reciprocal
#pragma unroll
    for (int mb = 0; mb < 8; ++mb) {
        float d = dd[mb];
        d += __shfl_xor(d, 16, 64);
        d += __shfl_xor(d, 32, 64);
        if (g == 0) den[qbase + mb * 16 + l15] = 1.0f / d;
    }
    __syncthreads();   // all waves done reading k_lds/vt

    // write unnormalized O^T (bf16) into k_lds region as sxT[16][520]
    unsigned short* sxT = k_lds;
#pragma unroll
    for (int mb = 0; mb < 8; ++mb) {
        uint2 t;
        t.x = f2bf(oacc[mb][0]) | ((unsigned)f2bf(oacc[mb][1]) << 16);
        t.y = f2bf(oacc[mb][2]) | ((unsigned)f2bf(oacc[mb][3]) << 16);
        const int q0 = qbase + mb * 16 + g * 4;   // C layout: rows = q, col = d = l15
        *(uint2*)(sxT + l15 * 520 + q0) = t;
    }
    __syncthreads();

    // pooling: out[c][d] = sum_n (cls[c][n]*rden[n]) * O[n][d]; wave w does n-blocks w*4..w*4+3
    f32x4 pacc0 = zf, pacc1 = zf;
    const float* clsb = cls_map + (size_t)bt * C_ * N_;
    for (int kk = 0; kk < 4; ++kk) {
        const int n0 = (w * 4 + kk) * 32;
        const short8 b8 = *(const short8*)(sxT + l15 * 520 + n0 + g * 8);
        const float4 rd0 = *(const float4*)(den + n0 + g * 8);
        const float4 rd1 = *(const float4*)(den + n0 + g * 8 + 4);
        const float* c0 = clsb + l15 * N_ + n0 + g * 8;
        const float* c1 = clsb + (16 + l15) * N_ + n0 + g * 8;
        float4 ca = *(const float4*)c0, cb = *(const float4*)(c0 + 4);
        U8 a0;
        a0.u[0] = f2bf(ca.x * rd0.x) | ((unsigned)f2bf(ca.y * rd0.y) << 16);
        a0.u[1] = f2bf(ca.z * rd0.z) | ((unsigned)f2bf(ca.w * rd0.w) << 16);
        a0.u[2] = f2bf(cb.x * rd1.x) | ((unsigned)f2bf(cb.y * rd1.y) << 16);
        a0.u[3] = f2bf(cb.z * rd1.z) | ((unsigned)f2bf(cb.w * rd1.w) << 16);
        pacc0 = __builtin_amdgcn_mfma_f32_16x16x32_bf16(a0.s8, b8, pacc0, 0, 0, 0);
        ca = *(const float4*)c1; cb = *(const float4*)(c1 + 4);
        U8 a1;
        a1.u[0] = f2bf(ca.x * rd0.x) | ((unsigned)f2bf(ca.y * rd0.y) << 16);
        a1.u[1] = f2bf(ca.z * rd0.z) | ((unsigned)f2bf(ca.w * rd0.w) << 16);
        a1.u[2] = f2bf(cb.x * rd1.x) | ((unsigned)f2bf(cb.y * rd1.y) << 16);
        a1.u[3] = f2bf(cb.z * rd1.z) | ((unsigned)f2bf(cb.w * rd1.w) << 16);
        pacc1 = __builtin_amdgcn_mfma_f32_16x16x32_bf16(a1.s8, b8, pacc1, 0, 0, 0);
    }
    // partial reduction across waves via LDS (overlay vt region)
    float* part = (float*)vt;                    // [8][256] = [w*2+mt][row*16+col]
#pragma unroll
    for (int r = 0; r < 4; ++r) {
        part[(w * 2 + 0) * 256 + (g * 4 + r) * 16 + l15] = pacc0[r];
        part[(w * 2 + 1) * 256 + (g * 4 + r) * 16 + l15] = pacc1[r];
    }
    __syncthreads();

    float* ob = out + (size_t)bt * C_ * HID_;
    for (int o = tid; o < 512; o += 256) {
        const int c = o >> 4, dc = o & 15;
        const int mt = c >> 4, rr = c & 15;
        const int idx = mt * 256 + rr * 16 + dc;
        const float s = part[idx] + part[512 + idx] + part[1024 + idx] + part[1536 + idx];
        ob[c * HID_ + h * HD_ + dc] = s;
    }
}

extern "C" void kernel_launch(void* const* d_in, const int* in_sizes, int n_in,
                              void* d_out, int out_size, void* d_ws, size_t ws_size,
                              hipStream_t stream) {
    const float* x       = (const float*)d_in[0];
    const float* cls_map = (const float*)d_in[1];
    const float* Wq      = (const float*)d_in[2];
    const float* Wk      = (const float*)d_in[3];
    const float* Wv      = (const float*)d_in[4];
    float* out           = (float*)d_out;

    const size_t per = (size_t)BT_ * HEADS_ * N_ * HD_;   // 6,291,456 bf16 elems each
    unsigned short* qg = (unsigned short*)d_ws;
    unsigned short* kg = qg + per;
    unsigned short* vg = kg + per;

    qkv_proj<<<BT_ * 4, 256, 0, stream>>>(x, Wq, Wk, Wv, qg, kg, vg);
    attn_pool<<<BT_ * HEADS_, 256, 0, stream>>>(qg, kg, vg, cls_map, out);
}